// Round 10
// baseline (327.362 us; speedup 1.0000x reference)
//
#include <hip/hip_runtime.h>

#define N_NODES  100000
#define N_EDGES  1600000
#define N_GRAPHS 256
#define F        64

// ---------------------------------------------------------------------------
// R27. Evidence chain:
//  - R9 falsified the W-reload theory: W->LDS left FETCH identical (81.5MB)
//    and gather got SLOWER (94 vs 80.3). R0's wcol body is the proven local
//    optimum. NPW=13 twice-measured worse than 25 (89.7/93.7 vs 80.3).
//  - Across R0/R4/R9: total - gather == 99-103us ALWAYS (5 enqueues + eidx
//    global round-trip). Bodies estimate only ~30us -> ~10us/enqueue launch
//    overhead dominates prep. Fix: ONE kernel = per-bucket LDS sort (edges
//    never leave LDS) + R0 gather body (NPW=16, eidx/nbeg/nend now in LDS)
//    + last-block finalize (completion counter). 3 enqueues total.
//  - 391 blocks x 1024thr: all co-resident (2 blocks/CU, 24.6KB LDS, 32
//    waves/CU iff VGPR<=64 — R0 body measured 60; VGPR>64 is the watch item).
//  - R3: random 4B global writes cost a 64B line each -> sort stays LDS-local.
//  - R1: no min-waves VGPR cap. R6: no cooperative fusion.
// ---------------------------------------------------------------------------

#define CHUNK    8192
#define NCHUNK   196                     // ceil(N_EDGES / CHUNK)
#define NBUCK    391                     // ceil(N_NODES / 256), bucket = dst>>8
#define BCAP     5120                    // bucket cap: mean 4092, +16 sigma

#define CAST_ELEMS   (N_NODES * F / 4)   // 1,600,000 float4
#define CAST_BLOCKS  ((CAST_ELEMS + 1023) / 1024)   // 1563
#define BC_BLOCKS    (NCHUNK + CAST_BLOCKS)         // 1759

__device__ __forceinline__ unsigned short f2bf(float f) {
    unsigned int u = __float_as_uint(f);
    u += 0x7FFFu + ((u >> 16) & 1u);
    return (unsigned short)(u >> 16);
}
__device__ __forceinline__ float bfl(unsigned int u) { return __uint_as_float(u << 16); }
__device__ __forceinline__ float bfh(unsigned int u) { return __uint_as_float(u & 0xFFFF0000u); }

// ---------- K1: bucket binning (blocks [0,196)) + x->bf16 cast (rest) ----------
// R4/R9-verified body; first cast block also zeros out/denom.
__global__ __launch_bounds__(1024) void bin_cast_kernel(
        const int* __restrict__ src, const int* __restrict__ dst,
        const float* __restrict__ x, unsigned short* __restrict__ xh,
        unsigned int* __restrict__ pairs, int* __restrict__ balloc,
        float* __restrict__ out, float* __restrict__ denom) {
    int tid = threadIdx.x;
    int b   = blockIdx.x;

    if (b >= NCHUNK) {              // ---- streaming cast section ----
        if (b == NCHUNK) {          // fold: zero out/denom (consumed next kernel)
            for (int i = tid; i < N_GRAPHS * F; i += 1024) out[i] = 0.f;
            if (tid < N_GRAPHS) denom[tid] = 0.f;
        }
        int i = (b - NCHUNK) * 1024 + tid;
        if (i < CAST_ELEMS) {
            float4 v = ((const float4*)x)[i];
            ushort4 o;
            o.x = f2bf(v.x); o.y = f2bf(v.y); o.z = f2bf(v.z); o.w = f2bf(v.w);
            ((ushort4*)xh)[i] = o;
        }
        return;
    }

    // ---- bin section ----
    __shared__ int hist[NBUCK];
    __shared__ int roffs[NBUCK];
    __shared__ int curs[NBUCK];
    __shared__ int bbase[NBUCK];
    __shared__ int wsum[16];
    __shared__ unsigned int   stage[CHUNK];    // 32 KB
    __shared__ unsigned short bstage[CHUNK];   // 16 KB

    int base = b * CHUNK;
    int m    = min(CHUNK, N_EDGES - base);
    int lane = tid & 63;
    int wv   = tid >> 6;

    for (int k = tid; k < NBUCK; k += 1024) hist[k] = 0;
    __syncthreads();

    int de[8], se[8];
    #pragma unroll
    for (int r = 0; r < 8; ++r) {
        int e = tid + r * 1024;
        if (e < m) {
            de[r] = dst[base + e];
            se[r] = src[base + e];
            atomicAdd(&hist[de[r] >> 8], 1);
        } else {
            de[r] = -1; se[r] = 0;
        }
    }
    __syncthreads();

    int v = (tid < NBUCK) ? hist[tid] : 0;
    #pragma unroll
    for (int o = 1; o < 64; o <<= 1) {
        int u = __shfl_up(v, o, 64);
        if (lane >= o) v += u;
    }
    if (lane == 63) wsum[wv] = v;
    __syncthreads();
    if (tid < 16) {
        int s = wsum[tid];
        #pragma unroll
        for (int o = 1; o < 16; o <<= 1) {
            int u = __shfl_up(s, o, 64);
            if (tid >= o) s += u;
        }
        wsum[tid] = s;
    }
    __syncthreads();
    if (wv > 0) v += wsum[wv - 1];
    if (tid < NBUCK) {
        int excl = v - hist[tid];
        roffs[tid] = excl;
        curs[tid]  = excl;
        if (hist[tid] > 0)    // one global atomic per (block,bucket) run
            bbase[tid] = tid * BCAP + atomicAdd(&balloc[tid], hist[tid]);
    }
    __syncthreads();

    #pragma unroll
    for (int r = 0; r < 8; ++r) {
        if (de[r] >= 0) {
            int bk  = de[r] >> 8;
            int pos = atomicAdd(&curs[bk], 1);
            stage[pos]  = ((unsigned)(de[r] & 255) << 17) | (unsigned)se[r];
            bstage[pos] = (unsigned short)bk;
        }
    }
    __syncthreads();

    for (int e = tid; e < m; e += 1024) {
        int bk = bstage[e];
        pairs[bbase[bk] + (e - roffs[bk])] = stage[e];
    }
}

// ---------- K2: per-bucket LDS sort + gather/transform/pool + last-block fin ----
// 391 blocks x 1024 thr (16 waves). Phase A: counting-sort the bucket's ~4K
// edges INTO LDS (no global write-back). Phase B: wave w gathers nodes
// w*16..w*16+15 with the R0-proven body; eidx/nbeg/nend are LDS reads.
// Phase C: completion counter; last block divides out by denom.
__global__ __launch_bounds__(1024) void sort_gather_kernel(
        const unsigned short* __restrict__ xh,
        const unsigned int* __restrict__ pairs,
        const int*   __restrict__ balloc,
        const int*   __restrict__ batch,
        const float* __restrict__ Wg,   // [64,64] (k, f)
        const float* __restrict__ bg,
        const float* __restrict__ Wa,
        const float* __restrict__ ba,
        float*       __restrict__ out,
        float*       __restrict__ denom,
        unsigned int* __restrict__ done) {
    __shared__ int hist[256];
    __shared__ int curs[256];
    __shared__ int lbeg[256];
    __shared__ int lend[256];
    __shared__ int wsum[4];
    __shared__ int sorted[BCAP];    // 20 KB, src indices grouped by node
    __shared__ int lastFlag;

    int tid  = threadIdx.x;
    int b    = blockIdx.x;
    int lane = tid & 63;
    int wv   = tid >> 6;
    int node0 = b << 8;
    int nn    = min(256, N_NODES - node0);
    int E     = balloc[b];
    int base  = b * BCAP;

    // ---- Phase A: counting sort into LDS ----
    if (tid < 256) hist[tid] = 0;
    __syncthreads();
    for (int i = tid; i < E; i += 1024)
        atomicAdd(&hist[pairs[base + i] >> 17], 1);
    __syncthreads();

    int c = (tid < 256) ? hist[tid] : 0;
    int v = c;
    #pragma unroll
    for (int o = 1; o < 64; o <<= 1) {
        int u = __shfl_up(v, o, 64);
        if (lane >= o) v += u;
    }
    if (tid < 256 && lane == 63) wsum[wv] = v;
    __syncthreads();
    if (tid < 4) {
        int s = wsum[tid];
        int u = __shfl_up(s, 1, 64); if (tid >= 1) s += u;
        u     = __shfl_up(s, 2, 64); if (tid >= 2) s += u;
        wsum[tid] = s;
    }
    __syncthreads();
    if (tid < 256) {
        if (wv > 0) v += wsum[wv - 1];
        int excl = v - c;
        curs[tid] = excl;
        lbeg[tid] = excl;
        lend[tid] = excl + c;
    }
    __syncthreads();

    for (int i = tid; i < E; i += 1024) {
        unsigned int p = pairs[base + i];
        int pos = atomicAdd(&curs[p >> 17], 1);
        sorted[pos] = (int)(p & 0x1FFFFu);
    }
    __syncthreads();

    // ---- Phase B: gather (R0-proven body; eidx/nbeg/nend from LDS) ----
    int grp = lane >> 3;   // 0..7: row within an 8-row gather batch
    int cc  = lane & 7;    // 16-B chunk (8 bf16) within a row

    float wcol[F];
    #pragma unroll
    for (int k = 0; k < F; ++k) wcol[k] = Wg[k * F + lane];
    float bgl = bg[lane];
    float wal = Wa[lane];
    float ba0 = ba[0];

    const uint4* xh4 = (const uint4*)xh;     // row = 8 uint4

    int nl0 = wv * 16;                 // local node start for this wave
    int myn = nn - nl0; if (myn > 16) myn = 16;

    if (myn > 0) {
        int   cur_g = batch[node0 + nl0];
        float accw  = 0.f;
        float denw  = 0.f;

        int pb = lbeg[nl0];
        int pe = lend[nl0];
        int sl_cur = (pb + lane < pe) ? sorted[pb + lane] : 0;

        for (int q = 0; q < myn; ++q) {
            int n = node0 + nl0 + q;
            int start = pb, end = pe;
            int sl    = sl_cur;
            if (q + 1 < myn) {     // prefetch next node's first edge chunk
                pb = lbeg[nl0 + q + 1];
                pe = lend[nl0 + q + 1];
                sl_cur = (pb + lane < pe) ? sorted[pb + lane] : 0;
            }

            float a0=0.f,a1=0.f,a2=0.f,a3=0.f,a4=0.f,a5=0.f,a6=0.f,a7=0.f;
            {
                int jmax = end - start; if (jmax > 64) jmax = 64;
                for (int j = 0; j < jmax; j += 8) {
                    int el = j + grp;
                    int s  = __shfl(sl, el, 64);
                    if (el < jmax) {
                        uint4 vv = xh4[s * 8 + cc];   // 16 B/lane
                        a0 += bfl(vv.x); a1 += bfh(vv.x);
                        a2 += bfl(vv.y); a3 += bfh(vv.y);
                        a4 += bfl(vv.z); a5 += bfh(vv.z);
                        a6 += bfl(vv.w); a7 += bfh(vv.w);
                    }
                }
            }
            for (int b2 = start + 64; b2 < end; b2 += 64) {   // deg > 64
                int jmax = end - b2; if (jmax > 64) jmax = 64;
                int sl2 = (b2 + lane < end) ? sorted[b2 + lane] : 0;
                for (int j = 0; j < jmax; j += 8) {
                    int el = j + grp;
                    int s  = __shfl(sl2, el, 64);
                    if (el < jmax) {
                        uint4 vv = xh4[s * 8 + cc];
                        a0 += bfl(vv.x); a1 += bfh(vv.x);
                        a2 += bfl(vv.y); a3 += bfh(vv.y);
                        a4 += bfl(vv.z); a5 += bfh(vv.z);
                        a6 += bfl(vv.w); a7 += bfh(vv.w);
                    }
                }
            }
            #pragma unroll
            for (int o = 8; o <= 32; o <<= 1) {
                a0 += __shfl_xor(a0, o, 64); a1 += __shfl_xor(a1, o, 64);
                a2 += __shfl_xor(a2, o, 64); a3 += __shfl_xor(a3, o, 64);
                a4 += __shfl_xor(a4, o, 64); a5 += __shfl_xor(a5, o, 64);
                a6 += __shfl_xor(a6, o, 64); a7 += __shfl_xor(a7, o, 64);
            }
            {
                uint4 vv = xh4[n * 8 + cc];   // self row
                a0 += bfl(vv.x); a1 += bfh(vv.x);
                a2 += bfl(vv.y); a3 += bfh(vv.y);
                a4 += bfl(vv.z); a5 += bfh(vv.z);
                a6 += bfl(vv.w); a7 += bfh(vv.w);
            }

            float re[8] = {a0,a1,a2,a3,a4,a5,a6,a7};
            float q0=0.f,q1=0.f,q2=0.f,q3=0.f,q4=0.f,q5=0.f,q6=0.f,q7=0.f;
            #pragma unroll
            for (int k = 0; k < F; k += 8) {
                int ln = k >> 3;
                q0 += __int_as_float(__builtin_amdgcn_readlane(__float_as_int(re[0]), ln)) * wcol[k + 0];
                q1 += __int_as_float(__builtin_amdgcn_readlane(__float_as_int(re[1]), ln)) * wcol[k + 1];
                q2 += __int_as_float(__builtin_amdgcn_readlane(__float_as_int(re[2]), ln)) * wcol[k + 2];
                q3 += __int_as_float(__builtin_amdgcn_readlane(__float_as_int(re[3]), ln)) * wcol[k + 3];
                q4 += __int_as_float(__builtin_amdgcn_readlane(__float_as_int(re[4]), ln)) * wcol[k + 4];
                q5 += __int_as_float(__builtin_amdgcn_readlane(__float_as_int(re[5]), ln)) * wcol[k + 5];
                q6 += __int_as_float(__builtin_amdgcn_readlane(__float_as_int(re[6]), ln)) * wcol[k + 6];
                q7 += __int_as_float(__builtin_amdgcn_readlane(__float_as_int(re[7]), ln)) * wcol[k + 7];
            }
            float hv = ((q0 + q1) + (q2 + q3)) + ((q4 + q5) + (q6 + q7)) + bgl;
            hv = hv > 0.f ? hv : 0.f;

            float p = hv * wal;
            #pragma unroll
            for (int o = 32; o > 0; o >>= 1)
                p += __shfl_down(p, o, 64);
            float s = __int_as_float(__builtin_amdgcn_readlane(__float_as_int(p), 0)) + ba0;
            float e = __expf(s);    // unshifted: softmax ratio is shift-invariant

            int g = batch[n];       // wave-uniform
            if (g != cur_g) {
                atomicAdd(&out[cur_g * F + lane], accw);
                if (lane == 0) atomicAdd(&denom[cur_g], denw);
                accw = 0.f; denw = 0.f; cur_g = g;
            }
            accw += e * hv;
            denw += e;
        }
        atomicAdd(&out[cur_g * F + lane], accw);
        if (lane == 0) atomicAdd(&denom[cur_g], denw);
    }

    // ---- Phase C: last block finalizes out /= denom ----
    __threadfence();             // make this block's atomics visible
    __syncthreads();
    if (tid == 0) {
        unsigned int prev = atomicAdd(done, 1u);
        lastFlag = (prev == (unsigned)(gridDim.x - 1)) ? 1 : 0;
    }
    __syncthreads();
    if (lastFlag) {
        for (int i = tid; i < N_GRAPHS * F; i += 1024) {
            float d = __hip_atomic_load(&denom[i >> 6], __ATOMIC_RELAXED,
                                        __HIP_MEMORY_SCOPE_AGENT);
            float o = __hip_atomic_load(&out[i], __ATOMIC_RELAXED,
                                        __HIP_MEMORY_SCOPE_AGENT);
            out[i] = (d > 0.f) ? o / d : 0.f;
        }
    }
}

extern "C" void kernel_launch(void* const* d_in, const int* in_sizes, int n_in,
                              void* d_out, int out_size, void* d_ws, size_t ws_size,
                              hipStream_t stream) {
    const float* x     = (const float*)d_in[0];
    const int*   ei    = (const int*)d_in[1];   // [2, N_EDGES]
    const int*   batch = (const int*)d_in[2];   // [N_NODES]
    const float* Wg    = (const float*)d_in[3];
    const float* bg    = (const float*)d_in[4];
    const float* Wa    = (const float*)d_in[5];
    const float* ba    = (const float*)d_in[6];
    float* out = (float*)d_out;

    const int* src = ei;
    const int* dst = ei + N_EDGES;

    // workspace layout (bytes), ~20.8 MB
    char* ws = (char*)d_ws;
    unsigned short* xh     = (unsigned short*)(ws);            // 12,800,000
    unsigned int*   pairs  = (unsigned int*)(ws + 12800000);   //  8,007,680
    int*            balloc = (int*)(ws + 20807680);            //      2,048
    unsigned int*   done   = (unsigned int*)(ws + 20809728);   //        256
    float*          denom  = (float*)(ws + 20809984);          //      1,024

    hipMemsetAsync(balloc, 0, 2048 + 256, stream);   // balloc + done
    bin_cast_kernel  <<<BC_BLOCKS, 1024, 0, stream>>>(src, dst, x, xh, pairs,
                                                      balloc, out, denom);
    sort_gather_kernel<<<NBUCK, 1024, 0, stream>>>(xh, pairs, balloc, batch,
                                                   Wg, bg, Wa, ba, out, denom, done);
}

// Round 11
// 184.526 us; speedup vs baseline: 1.7741x; 1.7741x over previous
//
#include <hip/hip_runtime.h>

#define N_NODES  100000
#define N_EDGES  1600000
#define N_GRAPHS 256
#define F        64

// ---------------------------------------------------------------------------
// R28. Evidence chain:
//  - R10: 3-enqueue pipeline residual = 90us for memset+bin_cast -> bin_cast
//    body is ~75-85us (NOT launch overhead). Its cast blocks (1563) each
//    alloc the bin section's 54KB LDS + 1024 thr to move ONE float4/thread
//    -> LDS-slot/block-turnover bound. Fix: split kernels; cast rides in the
//    25KB/512-thr sortcast kernel with a real grid-stride loop.
//  - R10 also: 3rd failed fusion (1024-thr blocks, 237us). No more fusion.
//  - R9: W-reload theory falsified (FETCH unchanged); R0 gather body with
//    wcol[] + NPW=25 is the proven optimum (80.3-80.5us x3 measurements).
//    NPW=13 twice worse. Keep gather VERBATIM.
//  - R3: random 4B global writes cost a 64B line each -> all scatter stays
//    LDS-staged/block-local. R1: no min-waves VGPR cap.
// Pipeline (5 enqueues, same count as R4's 179.3 -> isolates the theory):
//   memset(balloc) -> bin(196x1024) -> sortcast(2000x512) ->
//   gather(1000x256) -> fin(64x256).
// ---------------------------------------------------------------------------

#define CHUNK    8192
#define NCHUNK   196                     // ceil(N_EDGES / CHUNK)
#define NBUCK    391                     // ceil(N_NODES / 256), bucket = dst>>8
#define BCAP     5120                    // bucket cap: mean 4092, +16 sigma

#define CAST_ELEMS  (N_NODES * F / 4)    // 1,600,000 float4
#define SC_BLOCKS   2000                 // 391 sort + 1609 cast blocks

__device__ __forceinline__ unsigned short f2bf(float f) {
    unsigned int u = __float_as_uint(f);
    u += 0x7FFFu + ((u >> 16) & 1u);
    return (unsigned short)(u >> 16);
}
__device__ __forceinline__ float bfl(unsigned int u) { return __uint_as_float(u << 16); }
__device__ __forceinline__ float bfh(unsigned int u) { return __uint_as_float(u & 0xFFFF0000u); }

// ---------- K1: bucket binning (R4-verified bin body, cast removed) ----------
__global__ __launch_bounds__(1024) void bin_kernel(
        const int* __restrict__ src, const int* __restrict__ dst,
        unsigned int* __restrict__ pairs, int* __restrict__ balloc) {
    __shared__ int hist[NBUCK];
    __shared__ int roffs[NBUCK];
    __shared__ int curs[NBUCK];
    __shared__ int bbase[NBUCK];
    __shared__ int wsum[16];
    __shared__ unsigned int   stage[CHUNK];    // 32 KB
    __shared__ unsigned short bstage[CHUNK];   // 16 KB

    int tid  = threadIdx.x;
    int b    = blockIdx.x;
    int base = b * CHUNK;
    int m    = min(CHUNK, N_EDGES - base);
    int lane = tid & 63;
    int wv   = tid >> 6;

    for (int k = tid; k < NBUCK; k += 1024) hist[k] = 0;
    __syncthreads();

    int de[8], se[8];
    #pragma unroll
    for (int r = 0; r < 8; ++r) {
        int e = tid + r * 1024;
        if (e < m) {
            de[r] = dst[base + e];
            se[r] = src[base + e];
            atomicAdd(&hist[de[r] >> 8], 1);
        } else {
            de[r] = -1; se[r] = 0;
        }
    }
    __syncthreads();

    int v = (tid < NBUCK) ? hist[tid] : 0;
    #pragma unroll
    for (int o = 1; o < 64; o <<= 1) {
        int u = __shfl_up(v, o, 64);
        if (lane >= o) v += u;
    }
    if (lane == 63) wsum[wv] = v;
    __syncthreads();
    if (tid < 16) {
        int s = wsum[tid];
        #pragma unroll
        for (int o = 1; o < 16; o <<= 1) {
            int u = __shfl_up(s, o, 64);
            if (tid >= o) s += u;
        }
        wsum[tid] = s;
    }
    __syncthreads();
    if (wv > 0) v += wsum[wv - 1];
    if (tid < NBUCK) {
        int excl = v - hist[tid];
        roffs[tid] = excl;
        curs[tid]  = excl;
        if (hist[tid] > 0)    // one global atomic per (block,bucket) run
            bbase[tid] = tid * BCAP + atomicAdd(&balloc[tid], hist[tid]);
    }
    __syncthreads();

    #pragma unroll
    for (int r = 0; r < 8; ++r) {
        if (de[r] >= 0) {
            int bk  = de[r] >> 8;
            int pos = atomicAdd(&curs[bk], 1);
            stage[pos]  = ((unsigned)(de[r] & 255) << 17) | (unsigned)se[r];
            bstage[pos] = (unsigned short)bk;
        }
    }
    __syncthreads();

    for (int e = tid; e < m; e += 1024) {
        int bk = bstage[e];
        pairs[bbase[bk] + (e - roffs[bk])] = stage[e];
    }
}

// ---------- K2: per-bucket counting sort (R4-verified, in-place) | cast ----------
__global__ __launch_bounds__(512) void sortcast_kernel(
        unsigned int* __restrict__ pairs,      // in: pairs, out: eidx (aliased)
        const int* __restrict__ balloc,
        int* __restrict__ nbeg, int* __restrict__ nend,
        const float* __restrict__ x, unsigned short* __restrict__ xh,
        float* __restrict__ out, float* __restrict__ denom) {
    __shared__ int hist[256];
    __shared__ int roffs[256];
    __shared__ int curs[256];
    __shared__ int wsum[8];
    __shared__ int sorted[BCAP];    // 20 KB

    int tid = threadIdx.x;
    int b   = blockIdx.x;

    if (b >= NBUCK) {               // ---- cast section (grid-stride) ----
        if (b == NBUCK) {           // fold: zero out/denom (consumed next kernel)
            for (int i = tid; i < N_GRAPHS * F; i += 512) out[i] = 0.f;
            if (tid < N_GRAPHS) denom[tid] = 0.f;
        }
        int i0      = (b - NBUCK) * 512 + tid;
        int cstride = (SC_BLOCKS - NBUCK) * 512;
        for (int i = i0; i < CAST_ELEMS; i += cstride) {
            float4 v = ((const float4*)x)[i];
            ushort4 o;
            o.x = f2bf(v.x); o.y = f2bf(v.y); o.z = f2bf(v.z); o.w = f2bf(v.w);
            ((ushort4*)xh)[i] = o;
        }
        return;
    }

    // ---- sort section (R4-verified body) ----
    int lane  = tid & 63;
    int wv    = tid >> 6;
    int node0 = b << 8;
    int nn    = min(256, N_NODES - node0);
    int E     = balloc[b];
    int base  = b * BCAP;

    for (int k = tid; k < 256; k += 512) hist[k] = 0;
    __syncthreads();
    for (int i = tid; i < E; i += 512)
        atomicAdd(&hist[pairs[base + i] >> 17], 1);
    __syncthreads();

    int c = (tid < 256) ? hist[tid] : 0;
    int v = c;
    #pragma unroll
    for (int o = 1; o < 64; o <<= 1) {
        int u = __shfl_up(v, o, 64);
        if (lane >= o) v += u;
    }
    if (tid < 256 && lane == 63) wsum[wv] = v;
    __syncthreads();
    if (tid < 4) {
        int s = wsum[tid];
        int u = __shfl_up(s, 1, 64); if (tid >= 1) s += u;
        u     = __shfl_up(s, 2, 64); if (tid >= 2) s += u;
        wsum[tid] = s;
    }
    __syncthreads();
    if (tid < 256) {
        if (wv > 0) v += wsum[wv - 1];
        int excl = v - c;
        roffs[tid] = excl;
        curs[tid]  = excl;
        if (tid < nn) {
            nbeg[node0 + tid] = base + excl;
            nend[node0 + tid] = base + excl + c;
        }
    }
    __syncthreads();

    for (int i = tid; i < E; i += 512) {
        unsigned int p = pairs[base + i];
        int pos = atomicAdd(&curs[p >> 17], 1);
        sorted[pos] = (int)(p & 0x1FFFFu);
    }
    __syncthreads();
    for (int i = tid; i < E; i += 512)
        pairs[base + i] = (unsigned int)sorted[i];
}

// ---------- K3: fused gather+transform+pool (R0/R4-proven body, VERBATIM) ----------
#define NODES_PER_WAVE 25
#define GT_NWAVES  (N_NODES / NODES_PER_WAVE)   // 4000
#define GT_BLOCKS  (GT_NWAVES / 4)              // 1000

__global__ __launch_bounds__(256) void gather_pool_kernel(
        const unsigned short* __restrict__ xh,
        const int*   __restrict__ nbeg,
        const int*   __restrict__ nend,
        const int*   __restrict__ eidx,
        const int*   __restrict__ batch,
        const float* __restrict__ Wg,   // [64,64] (k, f)
        const float* __restrict__ bg,
        const float* __restrict__ Wa,
        const float* __restrict__ ba,
        float*       __restrict__ out_acc,   // [N_GRAPHS, F]
        float*       __restrict__ denom) {  // [N_GRAPHS]
    int tid  = threadIdx.x;
    int lane = tid & 63;
    int grp  = lane >> 3;   // 0..7: row within an 8-row gather batch
    int c    = lane & 7;    // 16-B chunk (8 bf16) within a row
    int waveId = blockIdx.x * 4 + (tid >> 6);

    int n0   = waveId * NODES_PER_WAVE;     // grid exactly covers N_NODES
    int nEnd = n0 + NODES_PER_WAVE;

    float wcol[F];
    #pragma unroll
    for (int k = 0; k < F; ++k) wcol[k] = Wg[k * F + lane];
    float bgl = bg[lane];
    float wal = Wa[lane];
    float ba0 = ba[0];

    const uint4* xh4 = (const uint4*)xh;     // row = 8 uint4

    int   cur_g = batch[n0];
    float accw  = 0.f;   // per-lane: sum e * h[lane]
    float denw  = 0.f;   // replicated: sum e

    int pb = nbeg[n0];
    int pe = nend[n0];
    int sl_cur = (pb + lane < pe) ? eidx[pb + lane] : 0;

    for (int n = n0; n < nEnd; ++n) {
        int start = pb, end = pe;
        int sl    = sl_cur;
        if (n + 1 < nEnd) {     // prefetch node n+1 while n's gathers fly
            pb = nbeg[n + 1];
            pe = nend[n + 1];
            sl_cur = (pb + lane < pe) ? eidx[pb + lane] : 0;
        }

        float a0=0.f,a1=0.f,a2=0.f,a3=0.f,a4=0.f,a5=0.f,a6=0.f,a7=0.f;
        {
            int jmax = end - start; if (jmax > 64) jmax = 64;
            for (int j = 0; j < jmax; j += 8) {
                int el = j + grp;
                int s  = __shfl(sl, el, 64);
                if (el < jmax) {
                    uint4 v = xh4[s * 8 + c];   // 16 B/lane, 8 rows/instr
                    a0 += bfl(v.x); a1 += bfh(v.x);
                    a2 += bfl(v.y); a3 += bfh(v.y);
                    a4 += bfl(v.z); a5 += bfh(v.z);
                    a6 += bfl(v.w); a7 += bfh(v.w);
                }
            }
        }
        for (int base2 = start + 64; base2 < end; base2 += 64) {  // deg > 64
            int jmax = end - base2; if (jmax > 64) jmax = 64;
            int sl2 = (base2 + lane < end) ? eidx[base2 + lane] : 0;
            for (int j = 0; j < jmax; j += 8) {
                int el = j + grp;
                int s  = __shfl(sl2, el, 64);
                if (el < jmax) {
                    uint4 v = xh4[s * 8 + c];
                    a0 += bfl(v.x); a1 += bfh(v.x);
                    a2 += bfl(v.y); a3 += bfh(v.y);
                    a4 += bfl(v.z); a5 += bfh(v.z);
                    a6 += bfl(v.w); a7 += bfh(v.w);
                }
            }
        }
        #pragma unroll
        for (int o = 8; o <= 32; o <<= 1) {
            a0 += __shfl_xor(a0, o, 64); a1 += __shfl_xor(a1, o, 64);
            a2 += __shfl_xor(a2, o, 64); a3 += __shfl_xor(a3, o, 64);
            a4 += __shfl_xor(a4, o, 64); a5 += __shfl_xor(a5, o, 64);
            a6 += __shfl_xor(a6, o, 64); a7 += __shfl_xor(a7, o, 64);
        }
        {
            uint4 v = xh4[n * 8 + c];   // self row
            a0 += bfl(v.x); a1 += bfh(v.x);
            a2 += bfl(v.y); a3 += bfh(v.y);
            a4 += bfl(v.z); a5 += bfh(v.z);
            a6 += bfl(v.w); a7 += bfh(v.w);
        }

        float re[8] = {a0,a1,a2,a3,a4,a5,a6,a7};
        float q0=0.f,q1=0.f,q2=0.f,q3=0.f,q4=0.f,q5=0.f,q6=0.f,q7=0.f;
        #pragma unroll
        for (int k = 0; k < F; k += 8) {
            int ln = k >> 3;
            q0 += __int_as_float(__builtin_amdgcn_readlane(__float_as_int(re[0]), ln)) * wcol[k + 0];
            q1 += __int_as_float(__builtin_amdgcn_readlane(__float_as_int(re[1]), ln)) * wcol[k + 1];
            q2 += __int_as_float(__builtin_amdgcn_readlane(__float_as_int(re[2]), ln)) * wcol[k + 2];
            q3 += __int_as_float(__builtin_amdgcn_readlane(__float_as_int(re[3]), ln)) * wcol[k + 3];
            q4 += __int_as_float(__builtin_amdgcn_readlane(__float_as_int(re[4]), ln)) * wcol[k + 4];
            q5 += __int_as_float(__builtin_amdgcn_readlane(__float_as_int(re[5]), ln)) * wcol[k + 5];
            q6 += __int_as_float(__builtin_amdgcn_readlane(__float_as_int(re[6]), ln)) * wcol[k + 6];
            q7 += __int_as_float(__builtin_amdgcn_readlane(__float_as_int(re[7]), ln)) * wcol[k + 7];
        }
        float hv = ((q0 + q1) + (q2 + q3)) + ((q4 + q5) + (q6 + q7)) + bgl;
        hv = hv > 0.f ? hv : 0.f;

        float p = hv * wal;
        #pragma unroll
        for (int o = 32; o > 0; o >>= 1)
            p += __shfl_down(p, o, 64);
        float s = __int_as_float(__builtin_amdgcn_readlane(__float_as_int(p), 0)) + ba0;
        float e = __expf(s);    // unshifted: softmax ratio is shift-invariant

        int g = batch[n];       // wave-uniform
        if (g != cur_g) {
            atomicAdd(&out_acc[cur_g * F + lane], accw);
            if (lane == 0) atomicAdd(&denom[cur_g], denw);
            accw = 0.f; denw = 0.f; cur_g = g;
        }
        accw += e * hv;
        denw += e;
    }
    atomicAdd(&out_acc[cur_g * F + lane], accw);
    if (lane == 0) atomicAdd(&denom[cur_g], denw);
}

// ---------- K4: out /= denom ----------
__global__ __launch_bounds__(256) void fin_kernel(
        float* __restrict__ out, const float* __restrict__ denom) {
    int i = blockIdx.x * 256 + threadIdx.x;
    if (i >= N_GRAPHS * F) return;
    float d = denom[i >> 6];
    out[i] = (d > 0.f) ? out[i] / d : 0.f;
}

extern "C" void kernel_launch(void* const* d_in, const int* in_sizes, int n_in,
                              void* d_out, int out_size, void* d_ws, size_t ws_size,
                              hipStream_t stream) {
    const float* x     = (const float*)d_in[0];
    const int*   ei    = (const int*)d_in[1];   // [2, N_EDGES]
    const int*   batch = (const int*)d_in[2];   // [N_NODES]
    const float* Wg    = (const float*)d_in[3];
    const float* bg    = (const float*)d_in[4];
    const float* Wa    = (const float*)d_in[5];
    const float* ba    = (const float*)d_in[6];
    float* out = (float*)d_out;

    const int* src = ei;
    const int* dst = ei + N_EDGES;

    // workspace layout (bytes), ~21.7 MB
    char* ws = (char*)d_ws;
    unsigned short* xh     = (unsigned short*)(ws);            // 12,800,000
    unsigned int*   pairs  = (unsigned int*)(ws + 12800000);   //  8,007,680 (doubles as eidx)
    int*            nbeg   = (int*)(ws + 20807680);            //    400,000
    int*            nend   = (int*)(ws + 21207808);            //    400,000
    int*            balloc = (int*)(ws + 21607936);            //      2,048
    float*          denom  = (float*)(ws + 21610240);          //      1,024

    hipMemsetAsync(balloc, 0, NBUCK * sizeof(int), stream);
    bin_kernel     <<<NCHUNK, 1024, 0, stream>>>(src, dst, pairs, balloc);
    sortcast_kernel<<<SC_BLOCKS, 512, 0, stream>>>(pairs, balloc, nbeg, nend,
                                                   x, xh, out, denom);
    gather_pool_kernel<<<GT_BLOCKS, 256, 0, stream>>>(
        xh, nbeg, nend, (const int*)pairs, batch, Wg, bg, Wa, ba, out, denom);
    fin_kernel     <<<64, 256, 0, stream>>>(out, denom);
}